// Round 1
// baseline (868.754 us; speedup 1.0000x reference)
//
#include <hip/hip_runtime.h>
#include <hip/hip_bf16.h>
#include <math.h>

#define IN_F    4096
#define OUT_F   4096
#define N_TOK   8192
#define GROUP   128
#define NSTAGE  4
#define NPAIRS  2048   // IN_F/2 pairs per stage
#define QMAXF   15.0

typedef unsigned short u16;
typedef __bf16 bf16x8 __attribute__((ext_vector_type(8)));
typedef float  f32x4  __attribute__((ext_vector_type(4)));

struct alignas(8) U16x4 { u16 x, y, z, w; };

__device__ __forceinline__ u16 f2bf(float f) {
    unsigned u = __float_as_uint(f);
    unsigned r = (u + 0x7fffu + ((u >> 16) & 1u)) >> 16;   // RNE
    return (u16)r;
}

__device__ __forceinline__ void gl_lds16(const void* g, void* l) {
    __builtin_amdgcn_global_load_lds(
        (const __attribute__((address_space(1))) void*)g,
        (__attribute__((address_space(3))) void*)l,
        16, 0, 0);
}

// ---------------------------------------------------------------- tables ----
__global__ void make_tabs(const float* __restrict__ theta,
                          double* __restrict__ ctab, double* __restrict__ stab) {
    int i = blockIdx.x * 256 + threadIdx.x;
    if (i < NSTAGE * NPAIRS) {
        double t = (double)theta[i];
        ctab[i] = cos(t);
        stab[i] = sin(t);
    }
}

// ------------------------------------------------------------- transform ----
// One block per output row. Row held in LDS as double for max fidelity to the
// numpy reference through the round() in quant-dequant.
__global__ __launch_bounds__(256) void build_w(
    const float* __restrict__ weight, const float* __restrict__ cs,
    const float* __restrict__ qs, const float* __restrict__ qzp,
    const int* __restrict__ pairs,
    const double* __restrict__ ctab, const double* __restrict__ stab,
    u16* __restrict__ wb) {
    __shared__ double row[IN_F];
    const int o = blockIdx.x;
    const int tid = threadIdx.x;
    const float* wr = weight + (size_t)o * IN_F;

    for (int e = tid; e < IN_F; e += 256)
        row[e] = (double)wr[e] * (double)cs[e];

    // forward rotation stages
    for (int r = 0; r < NSTAGE; ++r) {
        __syncthreads();
        for (int p = tid; p < NPAIRS; p += 256) {
            int g = p >> 6, q = p & 63;
            int i = pairs[r * IN_F + g * GROUP + 2 * q];
            int j = pairs[r * IN_F + g * GROUP + 2 * q + 1];
            int gi = g * GROUP + i, gj = g * GROUP + j;
            double c = ctab[r * NPAIRS + p], s = stab[r * NPAIRS + p];
            double xi = row[gi], xj = row[gj];
            row[gi] =  xi * c + xj * s;
            row[gj] = -xi * s + xj * c;
        }
    }
    __syncthreads();

    // group quant-dequant (16 contiguous elems per thread, all in one group)
    {
        int g = tid >> 3;                       // (tid*16)/128
        double s   = fmin(fmax((double)qs[o * 32 + g], 1e-5), 1e5);
        double rzp = fmin(fmax(-rint((double)qzp[o * 32 + g]), 0.0), QMAXF);
        int e0 = tid * 16;
        for (int e = e0; e < e0 + 16; ++e) {
            double q = rint(row[e] / s) + rzp;
            q = fmin(fmax(q, 0.0), QMAXF);
            row[e] = (q - rzp) * s;
        }
    }

    // inverse rotation stages (reversed order, negated theta)
    for (int r = NSTAGE - 1; r >= 0; --r) {
        __syncthreads();
        for (int p = tid; p < NPAIRS; p += 256) {
            int g = p >> 6, q = p & 63;
            int i = pairs[r * IN_F + g * GROUP + 2 * q];
            int j = pairs[r * IN_F + g * GROUP + 2 * q + 1];
            int gi = g * GROUP + i, gj = g * GROUP + j;
            double c = ctab[r * NPAIRS + p], s = stab[r * NPAIRS + p];
            double xi = row[gi], xj = row[gj];
            row[gi] = xi * c - xj * s;
            row[gj] = xi * s + xj * c;
        }
    }
    __syncthreads();

    for (int e = tid; e < IN_F; e += 256)
        wb[(size_t)o * IN_F + e] = f2bf((float)(row[e] / (double)cs[e]));
}

// ----------------------------------------------------------------- cast x ---
__global__ void cast_x(const float* __restrict__ x, u16* __restrict__ xb) {
    size_t i = ((size_t)blockIdx.x * 256 + threadIdx.x) * 4;
    float4 v = *(const float4*)(x + i);
    U16x4 o;
    o.x = f2bf(v.x); o.y = f2bf(v.y); o.z = f2bf(v.z); o.w = f2bf(v.w);
    *(U16x4*)(xb + i) = o;
}

// ------------------------------------------------------------------ GEMM ----
// C[m,n] = sum_k A[m,k] * B[n,k] + bias[n]   (A: M x K, B: N x K, both bf16)
// m97 structure: 128x128 block tile, BK=32, 4 waves each 64x64 (4x4 MFMA 16x16x32)
__global__ __launch_bounds__(256) void gemm_bt(
    const u16* __restrict__ A, const u16* __restrict__ B,
    const float* __restrict__ bias, float* __restrict__ C) {
    constexpr int K = IN_F;
    constexpr int N = OUT_F;
    __shared__ __align__(16) u16 As[128 * 32];
    __shared__ __align__(16) u16 Bs[128 * 32];

    const int tid  = threadIdx.x;
    const int wave = tid >> 6, lane = tid & 63;
    const int ntile = N / 128;                       // 32
    const int mt = blockIdx.x / ntile, nt = blockIdx.x % ntile;
    const int m0 = mt * 128, n0 = nt * 128;
    const u16* Ab = A + (size_t)m0 * K;
    const u16* Bb = B + (size_t)n0 * K;

    f32x4 acc[4][4];
#pragma unroll
    for (int i = 0; i < 4; ++i)
#pragma unroll
        for (int j = 0; j < 4; ++j) acc[i][j] = (f32x4){0.f, 0.f, 0.f, 0.f};

    const int lrow = lane & 15, lq = lane >> 4;
    const int mw = (wave >> 1) * 64, nw = (wave & 1) * 64;

    for (int k0 = 0; k0 < K; k0 += 32) {
        // stage A tile (128x32 bf16 = 16 KB): 4 rounds x 256 lanes x 16 B
#pragma unroll
        for (int r = 0; r < 4; ++r) {
            int c = r * 256 + tid;                   // 16B-chunk id
            int row = c >> 2, ch = (c & 3) << 3;
            gl_lds16(Ab + (size_t)row * K + (k0 + ch),
                     &As[(r * 256 + wave * 64) * 8]);
        }
#pragma unroll
        for (int r = 0; r < 4; ++r) {
            int c = r * 256 + tid;
            int row = c >> 2, ch = (c & 3) << 3;
            gl_lds16(Bb + (size_t)row * K + (k0 + ch),
                     &Bs[(r * 256 + wave * 64) * 8]);
        }
        __syncthreads();

        bf16x8 af[4], bfr[4];
#pragma unroll
        for (int i = 0; i < 4; ++i)
            af[i] = *(const bf16x8*)&As[(mw + i * 16 + lrow) * 32 + lq * 8];
#pragma unroll
        for (int j = 0; j < 4; ++j)
            bfr[j] = *(const bf16x8*)&Bs[(nw + j * 16 + lrow) * 32 + lq * 8];
#pragma unroll
        for (int i = 0; i < 4; ++i)
#pragma unroll
            for (int j = 0; j < 4; ++j)
                acc[i][j] = __builtin_amdgcn_mfma_f32_16x16x32_bf16(
                    af[i], bfr[j], acc[i][j], 0, 0, 0);
        __syncthreads();
    }

    // epilogue: C/D layout col = lane&15, row = (lane>>4)*4 + reg
#pragma unroll
    for (int i = 0; i < 4; ++i) {
        int rb = m0 + mw + i * 16 + lq * 4;
#pragma unroll
        for (int j = 0; j < 4; ++j) {
            int col = n0 + nw + j * 16 + lrow;
            float bv = bias[col];
#pragma unroll
            for (int r = 0; r < 4; ++r)
                C[(size_t)(rb + r) * N + col] = acc[i][j][r] + bv;
        }
    }
}

// ---------------------------------------------------------------- launch ----
extern "C" void kernel_launch(void* const* d_in, const int* in_sizes, int n_in,
                              void* d_out, int out_size, void* d_ws, size_t ws_size,
                              hipStream_t stream) {
    const float* x    = (const float*)d_in[0];
    const float* w    = (const float*)d_in[1];
    const float* bias = (const float*)d_in[2];
    const float* cs   = (const float*)d_in[3];
    const float* th   = (const float*)d_in[4];
    const float* qs   = (const float*)d_in[5];
    const float* qzp  = (const float*)d_in[6];
    const int*   pr   = (const int*)d_in[7];
    float* out = (float*)d_out;

    char* ws = (char*)d_ws;
    double* ctab = (double*)ws;                                  // 64 KB
    double* stab = (double*)(ws + 65536);                        // 64 KB
    u16*    xb   = (u16*)(ws + 131072);                          // 64 MB
    u16*    wb   = (u16*)(ws + 131072 + (size_t)N_TOK * IN_F * 2);  // 32 MB

    hipLaunchKernelGGL(make_tabs, dim3((NSTAGE * NPAIRS + 255) / 256), dim3(256),
                       0, stream, th, ctab, stab);
    hipLaunchKernelGGL(build_w, dim3(OUT_F), dim3(256), 0, stream,
                       w, cs, qs, qzp, pr, ctab, stab, wb);
    hipLaunchKernelGGL(cast_x, dim3(N_TOK * IN_F / 4 / 256), dim3(256), 0, stream,
                       x, xb);
    hipLaunchKernelGGL(gemm_bt, dim3((N_TOK / 128) * (OUT_F / 128)), dim3(256),
                       0, stream, xb, wb, bias, out);
}

// Round 2
// 652.779 us; speedup vs baseline: 1.3309x; 1.3309x over previous
//
#include <hip/hip_runtime.h>
#include <hip/hip_bf16.h>
#include <math.h>

#define IN_F    4096
#define OUT_F   4096
#define N_TOK   8192
#define GROUP   128
#define NSTAGE  4
#define NPAIRS  2048   // IN_F/2 pairs per stage
#define QMAXF   15.0

typedef unsigned short u16;
typedef __bf16 bf16x8 __attribute__((ext_vector_type(8)));
typedef float  f32x4  __attribute__((ext_vector_type(4)));

struct alignas(8) U16x4 { u16 x, y, z, w; };

__device__ __forceinline__ u16 f2bf(float f) {
    unsigned u = __float_as_uint(f);
    unsigned r = (u + 0x7fffu + ((u >> 16) & 1u)) >> 16;   // RNE
    return (u16)r;
}

__device__ __forceinline__ void gl_lds16(const void* g, void* l) {
    __builtin_amdgcn_global_load_lds(
        (const __attribute__((address_space(1))) void*)g,
        (__attribute__((address_space(3))) void*)l,
        16, 0, 0);
}

// ---------------------------------------------------------------- tables ----
__global__ void make_tabs(const float* __restrict__ theta,
                          double* __restrict__ ctab, double* __restrict__ stab) {
    int i = blockIdx.x * 256 + threadIdx.x;
    if (i < NSTAGE * NPAIRS) {
        double t = (double)theta[i];
        ctab[i] = cos(t);
        stab[i] = sin(t);
    }
}

// ------------------------------------------------------------- transform ----
// The whole chain (scale -> 4 rot -> qdq -> 4 inv-rot -> unscale) is
// block-diagonal per 128-elem group. One WAVE per (row, group): 1 pair per
// lane per stage, wave-synchronous LDS (no __syncthreads; compiler orders
// may-alias ds ops within the wave). Doubles for fidelity through round().
__global__ __launch_bounds__(256) void build_w(
    const float* __restrict__ weight, const float* __restrict__ cs,
    const float* __restrict__ qs, const float* __restrict__ qzp,
    const int* __restrict__ pairs,
    const double* __restrict__ ctab, const double* __restrict__ stab,
    u16* __restrict__ wb) {
    __shared__ double gbuf[4][GROUP];
    const int wave = threadIdx.x >> 6, l = threadIdx.x & 63;
    const int task = blockIdx.x * 4 + wave;        // 4096*32 tasks
    const int o = task >> 5, g = task & 31;
    double* gb = gbuf[wave];
    const int e0 = g * GROUP;

    float2 wv = *(const float2*)(weight + (size_t)o * IN_F + e0 + 2 * l);
    float2 cv = *(const float2*)(cs + e0 + 2 * l);
    gb[2 * l]     = (double)wv.x * (double)cv.x;
    gb[2 * l + 1] = (double)wv.y * (double)cv.y;
    __builtin_amdgcn_wave_barrier();

    const int2* prs = (const int2*)pairs;          // (i,j) pairs, 8B aligned

    // forward rotation stages
    for (int r = 0; r < NSTAGE; ++r) {
        int2 p = prs[r * (IN_F / 2) + g * 64 + l];
        double c = ctab[r * NPAIRS + g * 64 + l];
        double s = stab[r * NPAIRS + g * 64 + l];
        double xi = gb[p.x], xj = gb[p.y];
        __builtin_amdgcn_wave_barrier();
        gb[p.x] =  xi * c + xj * s;
        gb[p.y] = -xi * s + xj * c;
        __builtin_amdgcn_wave_barrier();
    }

    // group quant-dequant
    {
        double s   = fmin(fmax((double)qs[o * 32 + g], 1e-5), 1e5);
        double rzp = fmin(fmax(-rint((double)qzp[o * 32 + g]), 0.0), QMAXF);
#pragma unroll
        for (int e = 2 * l; e <= 2 * l + 1; ++e) {
            double q = rint(gb[e] / s) + rzp;
            q = fmin(fmax(q, 0.0), QMAXF);
            gb[e] = (q - rzp) * s;
        }
        __builtin_amdgcn_wave_barrier();
    }

    // inverse rotation stages
    for (int r = NSTAGE - 1; r >= 0; --r) {
        int2 p = prs[r * (IN_F / 2) + g * 64 + l];
        double c = ctab[r * NPAIRS + g * 64 + l];
        double s = stab[r * NPAIRS + g * 64 + l];
        double xi = gb[p.x], xj = gb[p.y];
        __builtin_amdgcn_wave_barrier();
        gb[p.x] = xi * c - xj * s;
        gb[p.y] = xi * s + xj * c;
        __builtin_amdgcn_wave_barrier();
    }

    unsigned lo = f2bf((float)(gb[2 * l]     / (double)cv.x));
    unsigned hi = f2bf((float)(gb[2 * l + 1] / (double)cv.y));
    *(unsigned*)(wb + (size_t)o * IN_F + e0 + 2 * l) = lo | (hi << 16);
}

// ----------------------------------------------------------------- cast x ---
__global__ void cast_x(const float* __restrict__ x, u16* __restrict__ xb) {
    size_t i = ((size_t)blockIdx.x * 256 + threadIdx.x) * 4;
    float4 v = *(const float4*)(x + i);
    U16x4 o;
    o.x = f2bf(v.x); o.y = f2bf(v.y); o.z = f2bf(v.z); o.w = f2bf(v.w);
    *(U16x4*)(xb + i) = o;
}

// ------------------------------------------------------------------ GEMM ----
// C[m,n] = sum_k A[m,k] * B[n,k] + bias[n]   (A: M x K, B: N x K, both bf16)
// m97 structure: 128x128 tile, BK=32, 4 waves each 64x64 (4x4 MFMA 16x16x32).
// LDS chunk swizzle: 16B chunk at (row,pos) holds global chunk pos^((row>>1)&3)
// -> quarter-wave ds_read_b128 is exactly 2-way per bank (free, m136).
__global__ __launch_bounds__(256) void gemm_bt(
    const u16* __restrict__ A, const u16* __restrict__ B,
    const float* __restrict__ bias, float* __restrict__ C) {
    constexpr int K = IN_F;
    constexpr int N = OUT_F;
    __shared__ __align__(16) u16 As[128 * 32];   // 8 KB
    __shared__ __align__(16) u16 Bs[128 * 32];   // 8 KB

    const int tid  = threadIdx.x;
    const int wave = tid >> 6, lane = tid & 63;
    const int ntile = N / 128;                       // 32
    const int mt = blockIdx.x / ntile, nt = blockIdx.x % ntile;
    const int m0 = mt * 128, n0 = nt * 128;
    const u16* Ab = A + (size_t)m0 * K;
    const u16* Bb = B + (size_t)n0 * K;

    f32x4 acc[4][4];
#pragma unroll
    for (int i = 0; i < 4; ++i)
#pragma unroll
        for (int j = 0; j < 4; ++j) acc[i][j] = (f32x4){0.f, 0.f, 0.f, 0.f};

    const int lrow = lane & 15, lq = lane >> 4;
    const int mw = (wave >> 1) * 64, nw = (wave & 1) * 64;

    // per-lane staging source (swizzled chunk within the row)
    const int sc0 = tid;            // chunk id round 0 (0..255)
    const int sc1 = 256 + tid;      // chunk id round 1 (256..511)
    const int srow0 = sc0 >> 2, sgch0 = ((sc0 ^ (srow0 >> 1)) & 3) << 3;
    const int srow1 = sc1 >> 2, sgch1 = ((sc1 ^ (srow1 >> 1)) & 3) << 3;

    for (int k0 = 0; k0 < K; k0 += 32) {
        // A tile: 128x32 bf16 = 8 KB = 2 rounds of 256 lanes x 16 B
        gl_lds16(Ab + (size_t)srow0 * K + (k0 + sgch0), &As[(wave * 64) * 8]);
        gl_lds16(Ab + (size_t)srow1 * K + (k0 + sgch1), &As[(256 + wave * 64) * 8]);
        gl_lds16(Bb + (size_t)srow0 * K + (k0 + sgch0), &Bs[(wave * 64) * 8]);
        gl_lds16(Bb + (size_t)srow1 * K + (k0 + sgch1), &Bs[(256 + wave * 64) * 8]);
        __syncthreads();

        bf16x8 af[4], bfr[4];
#pragma unroll
        for (int i = 0; i < 4; ++i) {
            int ar = mw + i * 16 + lrow;
            af[i] = *(const bf16x8*)&As[ar * 32 + (((lq ^ (ar >> 1)) & 3) << 3)];
        }
#pragma unroll
        for (int j = 0; j < 4; ++j) {
            int br = nw + j * 16 + lrow;
            bfr[j] = *(const bf16x8*)&Bs[br * 32 + (((lq ^ (br >> 1)) & 3) << 3)];
        }
#pragma unroll
        for (int i = 0; i < 4; ++i)
#pragma unroll
            for (int j = 0; j < 4; ++j)
                acc[i][j] = __builtin_amdgcn_mfma_f32_16x16x32_bf16(
                    af[i], bfr[j], acc[i][j], 0, 0, 0);
        __syncthreads();
    }

    // epilogue: C/D layout col = lane&15, row = (lane>>4)*4 + reg
#pragma unroll
    for (int i = 0; i < 4; ++i) {
        int rb = m0 + mw + i * 16 + lq * 4;
#pragma unroll
        for (int j = 0; j < 4; ++j) {
            int col = n0 + nw + j * 16 + lrow;
            float bv = bias[col];
#pragma unroll
            for (int r = 0; r < 4; ++r)
                C[(size_t)(rb + r) * N + col] = acc[i][j][r] + bv;
        }
    }
}

// ---------------------------------------------------------------- launch ----
extern "C" void kernel_launch(void* const* d_in, const int* in_sizes, int n_in,
                              void* d_out, int out_size, void* d_ws, size_t ws_size,
                              hipStream_t stream) {
    const float* x    = (const float*)d_in[0];
    const float* w    = (const float*)d_in[1];
    const float* bias = (const float*)d_in[2];
    const float* cs   = (const float*)d_in[3];
    const float* th   = (const float*)d_in[4];
    const float* qs   = (const float*)d_in[5];
    const float* qzp  = (const float*)d_in[6];
    const int*   pr   = (const int*)d_in[7];
    float* out = (float*)d_out;

    char* ws = (char*)d_ws;
    double* ctab = (double*)ws;                                  // 64 KB
    double* stab = (double*)(ws + 65536);                        // 64 KB
    u16*    xb   = (u16*)(ws + 131072);                          // 64 MB
    u16*    wb   = (u16*)(ws + 131072 + (size_t)N_TOK * IN_F * 2);  // 32 MB

    hipLaunchKernelGGL(make_tabs, dim3((NSTAGE * NPAIRS + 255) / 256), dim3(256),
                       0, stream, th, ctab, stab);
    hipLaunchKernelGGL(build_w, dim3(OUT_F * 32 / 4), dim3(256), 0, stream,
                       w, cs, qs, qzp, pr, ctab, stab, wb);
    hipLaunchKernelGGL(cast_x, dim3(N_TOK * IN_F / 4 / 256), dim3(256), 0, stream,
                       x, xb);
    hipLaunchKernelGGL(gemm_bt, dim3((N_TOK / 128) * (OUT_F / 128)), dim3(256),
                       0, stream, xb, wb, bias, out);
}